// Round 9
// baseline (254.805 us; speedup 1.0000x reference)
//
#include <hip/hip_runtime.h>
#include <hip/hip_bf16.h>
#include <cstddef>
#include <cstdint>

// Problem constants: B=4, T=2048, C=1024, NH=16, hs=64, M = B*T = 8192
#define B_DIM 4
#define T_DIM 2048
#define C_DIM 1024
#define NHEAD 16
#define HS    64
#define QKV_LD 3072   // fused QKV row stride (3*C)

// log2(e)/8 : folded into the Wq bf16 cast so QK^T emerges in exp2-domain.
#define QSCALE 0.18033688011112042f

typedef __attribute__((ext_vector_type(8))) short short8;   // 8 bf16 (MFMA A/B frag)
typedef __attribute__((ext_vector_type(4))) short short4v;  // 4 bf16 (8B store)
typedef __attribute__((ext_vector_type(4))) float f32x4;    // MFMA C/D frag

__device__ __forceinline__ short f2bf(float x) {
    __hip_bfloat16 b = __float2bfloat16(x);   // RNE
    return *reinterpret_cast<short*>(&b);
}

// async global->LDS, 16B per lane; LDS dest is wave-uniform base + lane*16.
__device__ __forceinline__ void load_lds16(const void* g, void* l) {
    __builtin_amdgcn_global_load_lds(
        (const __attribute__((address_space(1))) void*)(g),
        (__attribute__((address_space(3))) void*)(l),
        16, 0, 0);
}

// ---------------------------------------------------------------------------
// Fused cast: x (4096 blocks) + 4 weights (4 x 512 blocks) in ONE launch.
// Weights go to one contiguous bf16 region (Wq|Wk|Wv|Wo); Wq gets QSCALE.
// ---------------------------------------------------------------------------
#define XBLK 4096   // (M*C/8)/256
#define WBLK 512    // (C*C/8)/256

__global__ __launch_bounds__(256) void cast_all(
    const float* __restrict__ x,
    const float* __restrict__ wq, const float* __restrict__ wk,
    const float* __restrict__ wv, const float* __restrict__ wo,
    short* __restrict__ xb, short* __restrict__ wout)
{
    const int bid = blockIdx.x;
    const float* in;
    short* out;
    float scale;
    int i;
    if (bid < XBLK) {
        i = bid * 256 + threadIdx.x;
        in = x; out = xb; scale = 1.0f;
    } else {
        const int r = bid - XBLK;
        const int sel = r >> 9;                  // /WBLK
        i = (r & (WBLK - 1)) * 256 + threadIdx.x;
        in  = (sel == 0) ? wq : (sel == 1) ? wk : (sel == 2) ? wv : wo;
        out = wout + (size_t)sel * (WBLK * 256 * 8);
        scale = (sel == 0) ? QSCALE : 1.0f;
    }
    const float4* p = (const float4*)in + (size_t)i * 2;
    float4 a = p[0], b = p[1];
    short8 o;
    o[0]=f2bf(a.x*scale); o[1]=f2bf(a.y*scale); o[2]=f2bf(a.z*scale); o[3]=f2bf(a.w*scale);
    o[4]=f2bf(b.x*scale); o[5]=f2bf(b.y*scale); o[6]=f2bf(b.z*scale); o[7]=f2bf(b.w*scale);
    *((short8*)out + i) = o;
}

// ---------------------------------------------------------------------------
// 8-phase-style MFMA GEMM, BM=128 x BN=256: C[M,N] = A[M,K] @ B[N,K]^T,
// bf16 in, fp32 accum. BK=64, 8 waves (2M x 4N), 512 threads, acc[4][4]/wave.
// LDS 96 KiB double-buffered; grids are exact multiples of 256 (full rounds).
// OUT_MODE: 0 = fp32 out; 1 = bf16 out; 2 = QKV fused epilogue:
//   Q/K panels (n0 < 2048) -> bf16 to Cm[M,N];
//   V panels  (n0 >= 2048) -> bf16 TRANSPOSED direct to Vt[B*NH, HS, T].
// ---------------------------------------------------------------------------
template<int OUT_MODE>
__global__ __launch_bounds__(512, 2) void gemm_bt_8ph(
    const short* __restrict__ A,    // [M,K] bf16
    const short* __restrict__ Bm,   // [N,K] bf16
    void* __restrict__ Cm,          // [M,N]
    short* __restrict__ Vt,         // [B*NH, HS, T] (OUT_MODE==2 only)
    int M, int N, int K)
{
    __shared__ __align__(16) short lds[49152];   // 96 KiB

    // bijective XCD swizzle (gridDim.x % 8 == 0), then flat -> (bx,by)
    const int nbx = N >> 8;
    int wg = blockIdx.x;
    const int cpx = gridDim.x >> 3;
    wg = (wg & 7) * cpx + (wg >> 3);
    const int bx = wg % nbx, by = wg / nbx;
    const int m0 = by << 7, n0 = bx << 8;        // BM=128, BN=256

    const int t = threadIdx.x;
    const int w = t >> 6, lane = t & 63;
    const int l16 = lane & 15, quad = lane >> 4;
    const int wm = w >> 2, wn = w & 3;           // 2M x 4N waves

    // staging geometry: one call = 64 rows x 128B; thread -> (row, 16B chunk)
    const int rcall  = t >> 3;                   // 0..63
    const int schunk = (t & 7) ^ (rcall & 7);    // pre-swizzled source chunk
    const int dstoff = w * 512;                  // per-wave LDS base (w*8 rows * 64)

    const short* Ag = A  + (size_t)(m0 + rcall) * K + schunk * 8;
    const short* Bg = Bm + (size_t)(n0 + rcall) * K + schunk * 8;

    short* const Ab0 = lds;
    short* const Ab1 = lds + 8192;
    short* const Bb0 = lds + 16384;
    short* const Bb1 = lds + 32768;

    // frag read offsets (shorts), swizzled
    int aoff[4][2], boff[4][2];
    #pragma unroll
    for (int mf = 0; mf < 4; ++mf) {
        const int ar = wm * 64 + mf * 16 + l16;          // 0..127
        #pragma unroll
        for (int ks = 0; ks < 2; ++ks)
            aoff[mf][ks] = ar * 64 + (((ks * 4 + quad) ^ (ar & 7)) * 8);
    }
    #pragma unroll
    for (int nf = 0; nf < 4; ++nf) {
        const int br = wn * 64 + nf * 16 + l16;          // 0..255
        #pragma unroll
        for (int ks = 0; ks < 2; ++ks)
            boff[nf][ks] = br * 64 + (((ks * 4 + quad) ^ (br & 7)) * 8);
    }

    f32x4 acc[4][4];
    const f32x4 zero4 = {0.f, 0.f, 0.f, 0.f};
    #pragma unroll
    for (int mf = 0; mf < 4; ++mf)
        #pragma unroll
        for (int nf = 0; nf < 4; ++nf) acc[mf][nf] = zero4;

    const int NT = K >> 6;   // 64-wide K-tiles

    // one 64-row staging call
    #define ST64(gb, kt, ro, lb)                                               \
        load_lds16((gb) + (size_t)(ro) * K + (size_t)(kt) * 64,                \
                   (lb) + (ro) * 64 + dstoff)

    // prologue: t0.A (2), t0.B (4), t1.A (2)  -> 8 outstanding
    ST64(Ag, 0, 0, Ab0); ST64(Ag, 0, 64, Ab0);
    ST64(Bg, 0, 0, Bb0); ST64(Bg, 0, 64, Bb0);
    ST64(Bg, 0, 128, Bb0); ST64(Bg, 0, 192, Bb0);
    ST64(Ag, 1, 0, Ab1); ST64(Ag, 1, 64, Ab1);

    for (int kt = 0; kt < NT; ++kt) {
        short* Acur = (kt & 1) ? Ab1 : Ab0;
        short* Bcur = (kt & 1) ? Bb1 : Bb0;
        short* Bnx  = (kt & 1) ? Bb0 : Bb1;

        if (kt == NT - 1) asm volatile("s_waitcnt vmcnt(0)" ::: "memory");
        else              asm volatile("s_waitcnt vmcnt(2)" ::: "memory");
        __builtin_amdgcn_s_barrier();

        // ---- phase 0: B-frags (whole tile) + A-frags mf0,1 ----
        short8 bfr[4][2], af[2][2];
        #pragma unroll
        for (int nf = 0; nf < 4; ++nf)
            #pragma unroll
            for (int ks = 0; ks < 2; ++ks)
                bfr[nf][ks] = *(const short8*)(Bcur + boff[nf][ks]);
        #pragma unroll
        for (int mf = 0; mf < 2; ++mf)
            #pragma unroll
            for (int ks = 0; ks < 2; ++ks)
                af[mf][ks] = *(const short8*)(Acur + aoff[mf][ks]);

        if (kt + 1 < NT) { ST64(Bg, kt + 1, 0, Bnx); ST64(Bg, kt + 1, 64, Bnx); }

        __builtin_amdgcn_s_barrier();
        __builtin_amdgcn_s_setprio(1);
        #pragma unroll
        for (int mf = 0; mf < 2; ++mf)
            #pragma unroll
            for (int nf = 0; nf < 4; ++nf)
                #pragma unroll
                for (int ks = 0; ks < 2; ++ks)
                    acc[mf][nf] = __builtin_amdgcn_mfma_f32_16x16x32_bf16(
                        af[mf][ks], bfr[nf][ks], acc[mf][nf], 0, 0, 0);
        __builtin_amdgcn_s_setprio(0);
        __builtin_amdgcn_s_barrier();

        // ---- phase 1: A-frags mf2,3 ----
        short8 af2[2][2];
        #pragma unroll
        for (int mf = 0; mf < 2; ++mf)
            #pragma unroll
            for (int ks = 0; ks < 2; ++ks)
                af2[mf][ks] = *(const short8*)(Acur + aoff[2 + mf][ks]);

        if (kt + 1 < NT) { ST64(Bg, kt + 1, 128, Bnx); ST64(Bg, kt + 1, 192, Bnx); }

        __builtin_amdgcn_s_barrier();
        __builtin_amdgcn_s_setprio(1);
        #pragma unroll
        for (int mf = 0; mf < 2; ++mf)
            #pragma unroll
            for (int nf = 0; nf < 4; ++nf)
                #pragma unroll
                for (int ks = 0; ks < 2; ++ks)
                    acc[2 + mf][nf] = __builtin_amdgcn_mfma_f32_16x16x32_bf16(
                        af2[mf][ks], bfr[nf][ks], acc[2 + mf][nf], 0, 0, 0);
        __builtin_amdgcn_s_setprio(0);
        __builtin_amdgcn_s_barrier();

        // tail: just-freed A buffer -> prefetch (t+2).A
        if (kt + 2 < NT) {
            short* Aw = (kt & 1) ? Ab1 : Ab0;
            ST64(Ag, kt + 2, 0, Aw); ST64(Ag, kt + 2, 64, Aw);
        }
    }
    #undef ST64

    if (OUT_MODE == 2 && n0 >= 2 * C_DIM) {
        // V panel -> transposed write into Vt[B*NH, HS, T]
        const int b    = m0 >> 11;               // token block within one b
        const int tt0  = (m0 & 2047) + wm * 64 + quad * 4;
        #pragma unroll
        for (int nf = 0; nf < 4; ++nf) {
            const int vcol = (n0 - 2 * C_DIM) + wn * 64 + nf * 16 + l16;
            const int h    = vcol >> 6;          // head within b
            const int d    = vcol & 63;
            short* dcol = Vt + ((size_t)((b << 4) + h) * HS + d) * T_DIM;
            #pragma unroll
            for (int mf = 0; mf < 4; ++mf) {
                const int tt = tt0 + mf * 16;
                short4v o;
                o[0] = f2bf(acc[mf][nf][0]); o[1] = f2bf(acc[mf][nf][1]);
                o[2] = f2bf(acc[mf][nf][2]); o[3] = f2bf(acc[mf][nf][3]);
                *(short4v*)(dcol + tt) = o;
            }
        }
    } else {
        #pragma unroll
        for (int mf = 0; mf < 4; ++mf) {
            const int row_base = m0 + wm * 64 + mf * 16 + quad * 4;
            #pragma unroll
            for (int nf = 0; nf < 4; ++nf) {
                const int col = n0 + wn * 64 + nf * 16 + l16;
                #pragma unroll
                for (int r = 0; r < 4; ++r) {
                    const size_t idx = (size_t)(row_base + r) * N + col;
                    if (OUT_MODE != 0) ((short*)Cm)[idx] = f2bf(acc[mf][nf][r]);
                    else               ((float*)Cm)[idx] = acc[mf][nf][r];
                }
            }
        }
    }
}

// ---------------------------------------------------------------------------
// Flash attention v9: QSUB=2 (4 blocks/CU) + head-locality XCD swizzle +
// DOUBLE-BUFFERED K/V LDS with reg prefetch — ONE barrier per key-tile:
//   loop t: { write regs->LDS[t&1]; sync; issue t+1 global loads->regs;
//             compute from LDS[t&1]; }
//   Correct with a single barrier: iter t+2's writes to buf b are ordered
//   after iter t+1's barrier, which post-dates all iter-t reads of b.
//   Halves barrier count and hides the (L2-resident) K/V load latency
//   under ~700 cycles of MFMA/exp compute.
//  - [64][72] padded LDS rows (benign 2-way; beat XOR swizzle in R6).
//  - Q pre-scaled by log2(e)/8 at the Wq cast -> exp is a bare v_exp_f32.
//  - Row-sum l via MFMA against a ones B-fragment.
// S^T trick: A=K-frag, B=Q-frag -> D[key][q]; K rows permuted kappa^-1 so
// exp'd S^T regs concatenate directly into the PV A-fragment. No-max softmax.
// ---------------------------------------------------------------------------
#define QSUB 2

__global__ __launch_bounds__(256, 4) void attn_mfma3(
    const short* __restrict__ Qb,    // [B,T,QKV_LD], Q cols (pre-scaled)
    const short* __restrict__ Kb,    // [B,T,QKV_LD], K cols
    const short* __restrict__ Vt,    // [B*NH, HS, T]
    short* __restrict__ O)           // [B,T,C] bf16
{
    // head-locality decode: 8 heads pinned per XCD, 16 q-chunks per head
    const int bid  = blockIdx.x;
    const int slot = bid >> 3;
    const int head = ((bid & 7) << 3) + (slot >> 4);
    const int i0   = (slot & 15) * (64 * QSUB);
    const int b = head >> 4, h = head & 15;

    const int t    = threadIdx.x;
    const int w    = t >> 6;
    const int lane = t & 63;
    const int l16  = lane & 15;
    const int quad = lane >> 4;

    __shared__ short Ks[2][64][72];     // [buf][perm key][dim]
    __shared__ short Vts[2][64][72];    // [buf][dim][key]

    short8 qf[QSUB][2];
    #pragma unroll
    for (int sub = 0; sub < QSUB; ++sub) {
        const short* qrow = Qb
            + ((size_t)(b * T_DIM) + i0 + sub * 64 + w * 16 + l16) * QKV_LD + h * HS;
        qf[sub][0] = *(const short8*)(qrow + quad * 8);
        qf[sub][1] = *(const short8*)(qrow + 32 + quad * 8);
    }

    short8 onesv;
    #pragma unroll
    for (int j = 0; j < 8; ++j) onesv[j] = (short)0x3F80;

    const f32x4 zero4 = {0.f, 0.f, 0.f, 0.f};
    f32x4 oacc[QSUB][4];
    f32x4 lacc[QSUB];
    #pragma unroll
    for (int sub = 0; sub < QSUB; ++sub) {
        #pragma unroll
        for (int dg = 0; dg < 4; ++dg) oacc[sub][dg] = zero4;
        lacc[sub] = zero4;
    }

    const int sr = t >> 2;
    const int sc = (t & 3) * 16;
    const int krow = (sr & 32) | ((sr & 4) << 2) | ((sr & 24) >> 1) | (sr & 3);
    const short* kgbase = Kb + (size_t)(b * T_DIM) * QKV_LD + h * HS;
    const short* vgbase = Vt + ((size_t)head * HS + sr) * T_DIM;

    // prologue: tile 0 -> regs
    short8 kr0, kr1, vr0, vr1;
    {
        const short* kp = kgbase + (size_t)sr * QKV_LD + sc;
        kr0 = *(const short8*)kp;
        kr1 = *(const short8*)(kp + 8);
        vr0 = *(const short8*)(vgbase + sc);
        vr1 = *(const short8*)(vgbase + sc + 8);
    }

    const int NT = T_DIM / 64;   // 32 key-tiles
    for (int kt2 = 0; kt2 < NT; ++kt2) {
        const int buf = kt2 & 1;

        // write current tile's regs -> LDS[buf]
        *(short8*)&Ks[buf][krow][sc]     = kr0;
        *(short8*)&Ks[buf][krow][sc + 8] = kr1;
        *(short8*)&Vts[buf][sr][sc]      = vr0;
        *(short8*)&Vts[buf][sr][sc + 8]  = vr1;
        __syncthreads();                 // ONE barrier per tile

        // issue next tile's global loads; consumed at next iteration's write
        if (kt2 + 1 < NT) {
            const int j1 = (kt2 + 1) * 64;
            const short* kp = kgbase + (size_t)(j1 + sr) * QKV_LD + sc;
            kr0 = *(const short8*)kp;
            kr1 = *(const short8*)(kp + 8);
            const short* vp = vgbase + j1;
            vr0 = *(const short8*)(vp + sc);
            vr1 = *(const short8*)(vp + sc + 8);
        }

        // K/V MFMA fragments from LDS[buf]: read once, reuse for both subs
        short8 ka[4][2], va[4][2];
        #pragma unroll
        for (int kt = 0; kt < 4; ++kt) {
            ka[kt][0] = *(const short8*)&Ks[buf][kt * 16 + l16][quad * 8];
            ka[kt][1] = *(const short8*)&Ks[buf][kt * 16 + l16][32 + quad * 8];
            va[kt][0] = *(const short8*)&Vts[buf][kt * 16 + l16][quad * 8];
            va[kt][1] = *(const short8*)&Vts[buf][kt * 16 + l16][32 + quad * 8];
        }

        #pragma unroll
        for (int sub = 0; sub < QSUB; ++sub) {
            f32x4 s[4];
            #pragma unroll
            for (int kt = 0; kt < 4; ++kt) {
                f32x4 acc = zero4;
                acc = __builtin_amdgcn_mfma_f32_16x16x32_bf16(ka[kt][0], qf[sub][0], acc, 0, 0, 0);
                acc = __builtin_amdgcn_mfma_f32_16x16x32_bf16(ka[kt][1], qf[sub][1], acc, 0, 0, 0);
                s[kt] = acc;
            }

            short8 pa[2];
            #pragma unroll
            for (int hh = 0; hh < 2; ++hh) {
                #pragma unroll
                for (int c = 0; c < 2; ++c) {
                    f32x4 sv = s[2 * hh + c];
                    #pragma unroll
                    for (int r = 0; r < 4; ++r) {
                        float p = __builtin_amdgcn_exp2f(sv[r]);
                        pa[hh][c * 4 + r] = f2bf(p);
                    }
                }
            }

            lacc[sub] = __builtin_amdgcn_mfma_f32_16x16x32_bf16(pa[0], onesv, lacc[sub], 0, 0, 0);
            lacc[sub] = __builtin_amdgcn_mfma_f32_16x16x32_bf16(pa[1], onesv, lacc[sub], 0, 0, 0);

            #pragma unroll
            for (int dg = 0; dg < 4; ++dg) {
                oacc[sub][dg] = __builtin_amdgcn_mfma_f32_16x16x32_bf16(pa[0], va[dg][0], oacc[sub][dg], 0, 0, 0);
                oacc[sub][dg] = __builtin_amdgcn_mfma_f32_16x16x32_bf16(pa[1], va[dg][1], oacc[sub][dg], 0, 0, 0);
            }
        }
    }

    #pragma unroll
    for (int sub = 0; sub < QSUB; ++sub) {
        float linv[4];
        #pragma unroll
        for (int r = 0; r < 4; ++r) linv[r] = 1.0f / lacc[sub][r];

        #pragma unroll
        for (int r = 0; r < 4; ++r) {
            short* orow = O + ((size_t)(b * T_DIM) + i0 + sub * 64 + w * 16 + quad * 4 + r) * C_DIM + h * HS;
            #pragma unroll
            for (int dg = 0; dg < 4; ++dg)
                orow[dg * 16 + l16] = f2bf(oacc[sub][dg][r] * linv[r]);
        }
    }
}

// ---------------------------------------------------------------------------
// ws layout (bytes), NB = 2*M*C = 16.8MB, WB = 2*C*C = 2.1MB:
//   [0]      xb bf16 (reused as Ob after QKV gemm)
//   [NB]     QKVb bf16 [M,3C]  (3*NB; V cols unwritten — V goes direct to Vt)
//   [4NB]    Vt bf16 [B*NH,HS,T]
//   [5NB]    W3b (Wq|Wk|Wv rows, 3*WB) | Wob (WB)      total 92.4MB
// ---------------------------------------------------------------------------
extern "C" void kernel_launch(void* const* d_in, const int* in_sizes, int n_in,
                              void* d_out, int out_size, void* d_ws, size_t ws_size,
                              hipStream_t stream) {
    const float* x  = (const float*)d_in[0];
    const float* Wk = (const float*)d_in[1];
    const float* Wq = (const float*)d_in[2];
    const float* Wv = (const float*)d_in[3];
    const float* Wo = (const float*)d_in[4];
    float* out = (float*)d_out;

    const int M = B_DIM * T_DIM;                       // 8192
    const size_t NE = (size_t)M * C_DIM;               // 8.4M
    const size_t NB = 2 * NE;                          // bytes
    const size_t WB = (size_t)2 * C_DIM * C_DIM;

    char* ws = (char*)d_ws;
    short* xb   = (short*)(ws);
    short* Ob   = xb;                                  // reuse after QKV gemm
    short* QKVb = (short*)(ws + NB);
    short* Vtb  = (short*)(ws + 4 * NB);
    short* W3b  = (short*)(ws + 5 * NB);               // [3C, C] rows: Wq|Wk|Wv (then Wob)
    short* Wob  = (short*)(ws + 5 * NB + 3 * WB);

    // all casts in one launch (Wq pre-scaled by log2(e)/8)
    cast_all<<<dim3(XBLK + 4 * WBLK), 256, 0, stream>>>(
        x, Wq, Wk, Wv, Wo, xb, W3b);

    // fused QKV projection + V-transpose epilogue (grid 768 = 3 full rounds)
    gemm_bt_8ph<2><<<dim3((QKV_LD / 256) * (M / 128)), 512, 0, stream>>>(
        xb, W3b, QKVb, Vtb, M, QKV_LD, C_DIM);

    // attention (2x q-merge, 1024 blocks = 4 blocks/CU, head-locality swizzle)
    attn_mfma3<<<dim3(T_DIM / (64 * QSUB) * B_DIM * NHEAD), 256, 0, stream>>>(
        QKVb, QKVb + C_DIM, Vtb, Ob);

    // output projection (fp32 out; grid 256 = exactly 1 full round)
    gemm_bt_8ph<0><<<dim3((C_DIM / 256) * (M / 128)), 512, 0, stream>>>(
        Ob, Wob, out, nullptr, M, C_DIM, C_DIM);
}

// Round 10
// 252.147 us; speedup vs baseline: 1.0105x; 1.0105x over previous
//
#include <hip/hip_runtime.h>
#include <hip/hip_bf16.h>
#include <cstddef>
#include <cstdint>

// Problem constants: B=4, T=2048, C=1024, NH=16, hs=64, M = B*T = 8192
#define B_DIM 4
#define T_DIM 2048
#define C_DIM 1024
#define NHEAD 16
#define HS    64
#define QKV_LD 3072   // fused QKV row stride (3*C)

// log2(e)/8 : folded into the Wq bf16 cast so QK^T emerges in exp2-domain.
#define QSCALE 0.18033688011112042f

typedef __attribute__((ext_vector_type(8))) short short8;   // 8 bf16 (MFMA A/B frag)
typedef __attribute__((ext_vector_type(4))) short short4v;  // 4 bf16 (8B store)
typedef __attribute__((ext_vector_type(4))) float f32x4;    // MFMA C/D frag

__device__ __forceinline__ short f2bf(float x) {
    __hip_bfloat16 b = __float2bfloat16(x);   // RNE
    return *reinterpret_cast<short*>(&b);
}

// async global->LDS, 16B per lane; LDS dest is wave-uniform base + lane*16.
__device__ __forceinline__ void load_lds16(const void* g, void* l) {
    __builtin_amdgcn_global_load_lds(
        (const __attribute__((address_space(1))) void*)(g),
        (__attribute__((address_space(3))) void*)(l),
        16, 0, 0);
}

// ---------------------------------------------------------------------------
// Fused cast: x (4096 blocks) + 4 weights (4 x 512 blocks) in ONE launch.
// Weights go to one contiguous bf16 region (Wq|Wk|Wv|Wo); Wq gets QSCALE.
// ---------------------------------------------------------------------------
#define XBLK 4096   // (M*C/8)/256
#define WBLK 512    // (C*C/8)/256

__global__ __launch_bounds__(256) void cast_all(
    const float* __restrict__ x,
    const float* __restrict__ wq, const float* __restrict__ wk,
    const float* __restrict__ wv, const float* __restrict__ wo,
    short* __restrict__ xb, short* __restrict__ wout)
{
    const int bid = blockIdx.x;
    const float* in;
    short* out;
    float scale;
    int i;
    if (bid < XBLK) {
        i = bid * 256 + threadIdx.x;
        in = x; out = xb; scale = 1.0f;
    } else {
        const int r = bid - XBLK;
        const int sel = r >> 9;                  // /WBLK
        i = (r & (WBLK - 1)) * 256 + threadIdx.x;
        in  = (sel == 0) ? wq : (sel == 1) ? wk : (sel == 2) ? wv : wo;
        out = wout + (size_t)sel * (WBLK * 256 * 8);
        scale = (sel == 0) ? QSCALE : 1.0f;
    }
    const float4* p = (const float4*)in + (size_t)i * 2;
    float4 a = p[0], b = p[1];
    short8 o;
    o[0]=f2bf(a.x*scale); o[1]=f2bf(a.y*scale); o[2]=f2bf(a.z*scale); o[3]=f2bf(a.w*scale);
    o[4]=f2bf(b.x*scale); o[5]=f2bf(b.y*scale); o[6]=f2bf(b.z*scale); o[7]=f2bf(b.w*scale);
    *((short8*)out + i) = o;
}

// ---------------------------------------------------------------------------
// GEMM v4 "wide-wave": C[M,N] = A[M,K] @ B[N,K]^T, bf16 in, fp32 accum.
// BM=128 x BN=256, BK=32, 256 threads = 4 waves, EACH WAVE OWNS 128x64
// (acc[8][4]) -> 42.7 FLOP/LDS-byte (vs 32 for 64x64/wave) and 32-MFMA
// runs per barrier. LDS 48 KiB double-buffered -> 2 blocks/CU stagger.
// Counted-vmcnt depth-2 pipeline: stage tile t+2 while computing t.
// Grids stay exact multiples of 256: QKV 768 = 3 rounds, Oproj 256 = 1.
// K-accumulation order identical to previous kernel (bitwise-same C).
// OUT_MODE: 0 = fp32 out; 2 = QKV fused epilogue (V panels, n0>=2048,
// write bf16 TRANSPOSED direct to Vt[B*NH, HS, T]).
// T2: LDS linear for global_load_lds; 16B-chunk index XOR'd with (row&3)
// on the GLOBAL source address, same XOR on the ds_read side.
// ---------------------------------------------------------------------------
template<int OUT_MODE>
__global__ __launch_bounds__(256, 2) void gemm_bt_wide(
    const short* __restrict__ A,    // [M,K] bf16
    const short* __restrict__ Bm,   // [N,K] bf16
    void* __restrict__ Cm,          // [M,N]
    short* __restrict__ Vt,         // [B*NH, HS, T] (OUT_MODE==2 only)
    int M, int N, int K)
{
    __shared__ __align__(16) short lds[24576];   // 48 KiB
    short* const Ab0 = lds;                      // [128][32] = 4096 shorts
    short* const Ab1 = lds + 4096;
    short* const Bb0 = lds + 8192;               // [256][32] = 8192 shorts
    short* const Bb1 = lds + 16384;

    // bijective XCD swizzle (gridDim.x % 8 == 0), then flat -> (bx,by)
    const int nbx = N >> 8;
    int wg = blockIdx.x;
    const int cpx = gridDim.x >> 3;
    wg = (wg & 7) * cpx + (wg >> 3);
    const int bx = wg % nbx, by = wg / nbx;
    const int m0 = by << 7, n0 = bx << 8;        // BM=128, BN=256

    const int t = threadIdx.x;
    const int w = t >> 6, lane = t & 63;         // wave w owns cols w*64..+63
    const int l16 = lane & 15, quad = lane >> 4;

    // staging: one call = 64 rows x 64B; thread -> (row = t>>2, 16B chunk t&3)
    const int rcall  = t >> 2;                   // 0..63
    const int schunk = (t & 3) ^ (rcall & 3);    // pre-swizzled source chunk
    const short* Ag = A  + (size_t)(m0 + rcall) * K + schunk * 8;
    const short* Bg = Bm + (size_t)(n0 + rcall) * K + schunk * 8;

    // frag read offsets (shorts within a [rows][32] tile), swizzled:
    // LDS[r][c] = G[r][c ^ (r&3)]  ->  global k-quad q lives at slot q^(r&3)
    int aoff[8], boff[4];
    #pragma unroll
    for (int mf = 0; mf < 8; ++mf) {
        const int ar = mf * 16 + l16;            // 0..127
        aoff[mf] = ar * 32 + ((quad ^ (ar & 3)) * 8);
    }
    #pragma unroll
    for (int nf = 0; nf < 4; ++nf) {
        const int br = w * 64 + nf * 16 + l16;   // 0..255
        boff[nf] = br * 32 + ((quad ^ (br & 3)) * 8);
    }

    f32x4 acc[8][4];
    const f32x4 zero4 = {0.f, 0.f, 0.f, 0.f};
    #pragma unroll
    for (int mf = 0; mf < 8; ++mf)
        #pragma unroll
        for (int nf = 0; nf < 4; ++nf) acc[mf][nf] = zero4;

    const int NT = K >> 5;   // 32-wide K-tiles

    // stage 64 rows (4 KB): per-wave base + HW lane*16B = linear thread*16B
    #define STW(gb, kt, ro, lb)                                                \
        load_lds16((gb) + (size_t)(ro) * K + (size_t)(kt) * 32,                \
                   (lb) + (ro) * 32 + w * 512)

    // prologue: tiles 0 and 1 fully staged -> 12 outstanding
    STW(Ag, 0, 0, Ab0); STW(Ag, 0, 64, Ab0);
    STW(Bg, 0, 0, Bb0); STW(Bg, 0, 64, Bb0);
    STW(Bg, 0, 128, Bb0); STW(Bg, 0, 192, Bb0);
    STW(Ag, 1, 0, Ab1); STW(Ag, 1, 64, Ab1);
    STW(Bg, 1, 0, Bb1); STW(Bg, 1, 64, Bb1);
    STW(Bg, 1, 128, Bb1); STW(Bg, 1, 192, Bb1);

    for (int kt = 0; kt < NT; ++kt) {
        short* Ac = (kt & 1) ? Ab1 : Ab0;
        short* Bc = (kt & 1) ? Bb1 : Bb0;

        // tile kt's 6 calls retire; tile kt+1's 6 stay in flight
        if (kt == NT - 1) asm volatile("s_waitcnt vmcnt(0)" ::: "memory");
        else              asm volatile("s_waitcnt vmcnt(6)" ::: "memory");
        __builtin_amdgcn_s_barrier();

        // all frags for this tile (8 A + 4 B ds_read_b128)
        short8 af[8], bfr[4];
        #pragma unroll
        for (int mf = 0; mf < 8; ++mf) af[mf] = *(const short8*)(Ac + aoff[mf]);
        #pragma unroll
        for (int nf = 0; nf < 4; ++nf) bfr[nf] = *(const short8*)(Bc + boff[nf]);

        // reads complete -> safe for all waves to overwrite this buffer
        asm volatile("s_waitcnt lgkmcnt(0)" ::: "memory");
        __builtin_amdgcn_s_barrier();

        // stage tile kt+2 into the just-freed buffer; rides under MFMA
        if (kt + 2 < NT) {
            STW(Ag, kt + 2, 0, Ac); STW(Ag, kt + 2, 64, Ac);
            STW(Bg, kt + 2, 0, Bc); STW(Bg, kt + 2, 64, Bc);
            STW(Bg, kt + 2, 128, Bc); STW(Bg, kt + 2, 192, Bc);
        }

        __builtin_amdgcn_s_setprio(1);
        #pragma unroll
        for (int mf = 0; mf < 8; ++mf)
            #pragma unroll
            for (int nf = 0; nf < 4; ++nf)
                acc[mf][nf] = __builtin_amdgcn_mfma_f32_16x16x32_bf16(
                    af[mf], bfr[nf], acc[mf][nf], 0, 0, 0);
        __builtin_amdgcn_s_setprio(0);
    }
    #undef STW

    if (OUT_MODE == 2 && n0 >= 2 * C_DIM) {
        // V panel -> transposed write into Vt[B*NH, HS, T]
        const int b   = m0 >> 11;
        const int tt0 = (m0 & 2047) + quad * 4;
        #pragma unroll
        for (int nf = 0; nf < 4; ++nf) {
            const int vcol = (n0 - 2 * C_DIM) + w * 64 + nf * 16 + l16;
            const int h    = vcol >> 6;          // head within b
            const int d    = vcol & 63;
            short* dcol = Vt + ((size_t)((b << 4) + h) * HS + d) * T_DIM;
            #pragma unroll
            for (int mf = 0; mf < 8; ++mf) {
                const int tt = tt0 + mf * 16;
                short4v o;
                o[0] = f2bf(acc[mf][nf][0]); o[1] = f2bf(acc[mf][nf][1]);
                o[2] = f2bf(acc[mf][nf][2]); o[3] = f2bf(acc[mf][nf][3]);
                *(short4v*)(dcol + tt) = o;
            }
        }
    } else {
        #pragma unroll
        for (int mf = 0; mf < 8; ++mf) {
            const int row_base = m0 + mf * 16 + quad * 4;
            #pragma unroll
            for (int nf = 0; nf < 4; ++nf) {
                const int col = n0 + w * 64 + nf * 16 + l16;
                #pragma unroll
                for (int r = 0; r < 4; ++r) {
                    const size_t idx = (size_t)(row_base + r) * N + col;
                    if (OUT_MODE != 0) ((short*)Cm)[idx] = f2bf(acc[mf][nf][r]);
                    else               ((float*)Cm)[idx] = acc[mf][nf][r];
                }
            }
        }
    }
}

// ---------------------------------------------------------------------------
// Flash attention v9 (unchanged from R9): QSUB=2, 4 blocks/CU, head-locality
// XCD swizzle, double-buffered K/V LDS with reg prefetch (1 barrier/tile).
//  - [64][72] padded LDS rows; Q pre-scaled by log2(e)/8; l via ones-MFMA.
// S^T trick: A=K-frag, B=Q-frag -> D[key][q]; K rows permuted kappa^-1.
// ---------------------------------------------------------------------------
#define QSUB 2

__global__ __launch_bounds__(256, 4) void attn_mfma3(
    const short* __restrict__ Qb,    // [B,T,QKV_LD], Q cols (pre-scaled)
    const short* __restrict__ Kb,    // [B,T,QKV_LD], K cols
    const short* __restrict__ Vt,    // [B*NH, HS, T]
    short* __restrict__ O)           // [B,T,C] bf16
{
    const int bid  = blockIdx.x;
    const int slot = bid >> 3;
    const int head = ((bid & 7) << 3) + (slot >> 4);
    const int i0   = (slot & 15) * (64 * QSUB);
    const int b = head >> 4, h = head & 15;

    const int t    = threadIdx.x;
    const int w    = t >> 6;
    const int lane = t & 63;
    const int l16  = lane & 15;
    const int quad = lane >> 4;

    __shared__ short Ks[2][64][72];     // [buf][perm key][dim]
    __shared__ short Vts[2][64][72];    // [buf][dim][key]

    short8 qf[QSUB][2];
    #pragma unroll
    for (int sub = 0; sub < QSUB; ++sub) {
        const short* qrow = Qb
            + ((size_t)(b * T_DIM) + i0 + sub * 64 + w * 16 + l16) * QKV_LD + h * HS;
        qf[sub][0] = *(const short8*)(qrow + quad * 8);
        qf[sub][1] = *(const short8*)(qrow + 32 + quad * 8);
    }

    short8 onesv;
    #pragma unroll
    for (int j = 0; j < 8; ++j) onesv[j] = (short)0x3F80;

    const f32x4 zero4 = {0.f, 0.f, 0.f, 0.f};
    f32x4 oacc[QSUB][4];
    f32x4 lacc[QSUB];
    #pragma unroll
    for (int sub = 0; sub < QSUB; ++sub) {
        #pragma unroll
        for (int dg = 0; dg < 4; ++dg) oacc[sub][dg] = zero4;
        lacc[sub] = zero4;
    }

    const int sr = t >> 2;
    const int sc = (t & 3) * 16;
    const int krow = (sr & 32) | ((sr & 4) << 2) | ((sr & 24) >> 1) | (sr & 3);
    const short* kgbase = Kb + (size_t)(b * T_DIM) * QKV_LD + h * HS;
    const short* vgbase = Vt + ((size_t)head * HS + sr) * T_DIM;

    short8 kr0, kr1, vr0, vr1;
    {
        const short* kp = kgbase + (size_t)sr * QKV_LD + sc;
        kr0 = *(const short8*)kp;
        kr1 = *(const short8*)(kp + 8);
        vr0 = *(const short8*)(vgbase + sc);
        vr1 = *(const short8*)(vgbase + sc + 8);
    }

    const int NT = T_DIM / 64;
    for (int kt2 = 0; kt2 < NT; ++kt2) {
        const int buf = kt2 & 1;

        *(short8*)&Ks[buf][krow][sc]     = kr0;
        *(short8*)&Ks[buf][krow][sc + 8] = kr1;
        *(short8*)&Vts[buf][sr][sc]      = vr0;
        *(short8*)&Vts[buf][sr][sc + 8]  = vr1;
        __syncthreads();

        if (kt2 + 1 < NT) {
            const int j1 = (kt2 + 1) * 64;
            const short* kp = kgbase + (size_t)(j1 + sr) * QKV_LD + sc;
            kr0 = *(const short8*)kp;
            kr1 = *(const short8*)(kp + 8);
            const short* vp = vgbase + j1;
            vr0 = *(const short8*)(vp + sc);
            vr1 = *(const short8*)(vp + sc + 8);
        }

        short8 ka[4][2], va[4][2];
        #pragma unroll
        for (int kt = 0; kt < 4; ++kt) {
            ka[kt][0] = *(const short8*)&Ks[buf][kt * 16 + l16][quad * 8];
            ka[kt][1] = *(const short8*)&Ks[buf][kt * 16 + l16][32 + quad * 8];
            va[kt][0] = *(const short8*)&Vts[buf][kt * 16 + l16][quad * 8];
            va[kt][1] = *(const short8*)&Vts[buf][kt * 16 + l16][32 + quad * 8];
        }

        #pragma unroll
        for (int sub = 0; sub < QSUB; ++sub) {
            f32x4 s[4];
            #pragma unroll
            for (int kt = 0; kt < 4; ++kt) {
                f32x4 acc = zero4;
                acc = __builtin_amdgcn_mfma_f32_16x16x32_bf16(ka[kt][0], qf[sub][0], acc, 0, 0, 0);
                acc = __builtin_amdgcn_mfma_f32_16x16x32_bf16(ka[kt][1], qf[sub][1], acc, 0, 0, 0);
                s[kt] = acc;
            }

            short8 pa[2];
            #pragma unroll
            for (int hh = 0; hh < 2; ++hh) {
                #pragma unroll
                for (int c = 0; c < 2; ++c) {
                    f32x4 sv = s[2 * hh + c];
                    #pragma unroll
                    for (int r = 0; r < 4; ++r) {
                        float p = __builtin_amdgcn_exp2f(sv[r]);
                        pa[hh][c * 4 + r] = f2bf(p);
                    }
                }
            }

            lacc[sub] = __builtin_amdgcn_mfma_f32_16x16x32_bf16(pa[0], onesv, lacc[sub], 0, 0, 0);
            lacc[sub] = __builtin_amdgcn_mfma_f32_16x16x32_bf16(pa[1], onesv, lacc[sub], 0, 0, 0);

            #pragma unroll
            for (int dg = 0; dg < 4; ++dg) {
                oacc[sub][dg] = __builtin_amdgcn_mfma_f32_16x16x32_bf16(pa[0], va[dg][0], oacc[sub][dg], 0, 0, 0);
                oacc[sub][dg] = __builtin_amdgcn_mfma_f32_16x16x32_bf16(pa[1], va[dg][1], oacc[sub][dg], 0, 0, 0);
            }
        }
    }

    #pragma unroll
    for (int sub = 0; sub < QSUB; ++sub) {
        float linv[4];
        #pragma unroll
        for (int r = 0; r < 4; ++r) linv[r] = 1.0f / lacc[sub][r];

        #pragma unroll
        for (int r = 0; r < 4; ++r) {
            short* orow = O + ((size_t)(b * T_DIM) + i0 + sub * 64 + w * 16 + quad * 4 + r) * C_DIM + h * HS;
            #pragma unroll
            for (int dg = 0; dg < 4; ++dg)
                orow[dg * 16 + l16] = f2bf(oacc[sub][dg][r] * linv[r]);
        }
    }
}

// ---------------------------------------------------------------------------
// ws layout (bytes), NB = 2*M*C = 16.8MB, WB = 2*C*C = 2.1MB:
//   [0]      xb bf16 (reused as Ob after QKV gemm)
//   [NB]     QKVb bf16 [M,3C]  (3*NB; V cols unwritten — V goes direct to Vt)
//   [4NB]    Vt bf16 [B*NH,HS,T]
//   [5NB]    W3b (Wq|Wk|Wv rows, 3*WB) | Wob (WB)      total 92.4MB
// ---------------------------------------------------------------------------
extern "C" void kernel_launch(void* const* d_in, const int* in_sizes, int n_in,
                              void* d_out, int out_size, void* d_ws, size_t ws_size,
                              hipStream_t stream) {
    const float* x  = (const float*)d_in[0];
    const float* Wk = (const float*)d_in[1];
    const float* Wq = (const float*)d_in[2];
    const float* Wv = (const float*)d_in[3];
    const float* Wo = (const float*)d_in[4];
    float* out = (float*)d_out;

    const int M = B_DIM * T_DIM;                       // 8192
    const size_t NE = (size_t)M * C_DIM;               // 8.4M
    const size_t NB = 2 * NE;                          // bytes
    const size_t WB = (size_t)2 * C_DIM * C_DIM;

    char* ws = (char*)d_ws;
    short* xb   = (short*)(ws);
    short* Ob   = xb;                                  // reuse after QKV gemm
    short* QKVb = (short*)(ws + NB);
    short* Vtb  = (short*)(ws + 4 * NB);
    short* W3b  = (short*)(ws + 5 * NB);               // [3C, C] rows: Wq|Wk|Wv (then Wob)
    short* Wob  = (short*)(ws + 5 * NB + 3 * WB);

    // all casts in one launch (Wq pre-scaled by log2(e)/8)
    cast_all<<<dim3(XBLK + 4 * WBLK), 256, 0, stream>>>(
        x, Wq, Wk, Wv, Wo, xb, W3b);

    // fused QKV projection + V-transpose epilogue (grid 768, 2 blocks/CU)
    gemm_bt_wide<2><<<dim3((QKV_LD / 256) * (M / 128)), 256, 0, stream>>>(
        xb, W3b, QKVb, Vtb, M, QKV_LD, C_DIM);

    // attention (2x q-merge, 1024 blocks = 4 blocks/CU, head-locality swizzle)
    attn_mfma3<<<dim3(T_DIM / (64 * QSUB) * B_DIM * NHEAD), 256, 0, stream>>>(
        QKVb, QKVb + C_DIM, Vtb, Ob);

    // output projection (fp32 out; grid 256)
    gemm_bt_wide<0><<<dim3((C_DIM / 256) * (M / 128)), 256, 0, stream>>>(
        Ob, Wob, out, nullptr, M, C_DIM, C_DIM);
}

// Round 11
// 249.523 us; speedup vs baseline: 1.0212x; 1.0105x over previous
//
#include <hip/hip_runtime.h>
#include <hip/hip_bf16.h>
#include <cstddef>
#include <cstdint>

// Problem constants: B=4, T=2048, C=1024, NH=16, hs=64, M = B*T = 8192
#define B_DIM 4
#define T_DIM 2048
#define C_DIM 1024
#define NHEAD 16
#define HS    64
#define QKV_LD 3072   // fused QKV row stride (3*C)

// log2(e)/8 : folded into the Wq bf16 cast so QK^T emerges in exp2-domain.
#define QSCALE 0.18033688011112042f

typedef __attribute__((ext_vector_type(8))) short short8;   // 8 bf16 (MFMA A/B frag)
typedef __attribute__((ext_vector_type(4))) short short4v;  // 4 bf16 (8B store)
typedef __attribute__((ext_vector_type(4))) float f32x4;    // MFMA C/D frag

__device__ __forceinline__ short f2bf(float x) {
    __hip_bfloat16 b = __float2bfloat16(x);   // RNE
    return *reinterpret_cast<short*>(&b);
}

// async global->LDS, 16B per lane; LDS dest is wave-uniform base + lane*16.
__device__ __forceinline__ void load_lds16(const void* g, void* l) {
    __builtin_amdgcn_global_load_lds(
        (const __attribute__((address_space(1))) void*)(g),
        (__attribute__((address_space(3))) void*)(l),
        16, 0, 0);
}

// ---------------------------------------------------------------------------
// Fused cast: x (4096 blocks) + 4 weights (4 x 512 blocks) in ONE launch.
// Weights go to one contiguous bf16 region (Wq|Wk|Wv|Wo); Wq gets QSCALE.
// ---------------------------------------------------------------------------
#define XBLK 4096   // (M*C/8)/256
#define WBLK 512    // (C*C/8)/256

__global__ __launch_bounds__(256) void cast_all(
    const float* __restrict__ x,
    const float* __restrict__ wq, const float* __restrict__ wk,
    const float* __restrict__ wv, const float* __restrict__ wo,
    short* __restrict__ xb, short* __restrict__ wout)
{
    const int bid = blockIdx.x;
    const float* in;
    short* out;
    float scale;
    int i;
    if (bid < XBLK) {
        i = bid * 256 + threadIdx.x;
        in = x; out = xb; scale = 1.0f;
    } else {
        const int r = bid - XBLK;
        const int sel = r >> 9;                  // /WBLK
        i = (r & (WBLK - 1)) * 256 + threadIdx.x;
        in  = (sel == 0) ? wq : (sel == 1) ? wk : (sel == 2) ? wv : wo;
        out = wout + (size_t)sel * (WBLK * 256 * 8);
        scale = (sel == 0) ? QSCALE : 1.0f;
    }
    const float4* p = (const float4*)in + (size_t)i * 2;
    float4 a = p[0], b = p[1];
    short8 o;
    o[0]=f2bf(a.x*scale); o[1]=f2bf(a.y*scale); o[2]=f2bf(a.z*scale); o[3]=f2bf(a.w*scale);
    o[4]=f2bf(b.x*scale); o[5]=f2bf(b.y*scale); o[6]=f2bf(b.z*scale); o[7]=f2bf(b.w*scale);
    *((short8*)out + i) = o;
}

// ---------------------------------------------------------------------------
// GEMM "wide-wave" (QKV): BM=128 x BN=256, BK=32, 256 threads = 4 waves,
// each wave owns 128x64 (acc[8][4]) -> 2.67 MFMA per ds_read_b128, 32-MFMA
// runs per barrier. LDS 48 KiB double-buffered, 2 blocks/CU stagger.
// Counted-vmcnt depth-2 pipeline: stage tile t+2 while computing t.
// OUT_MODE: 0 = fp32 out; 2 = QKV fused epilogue (V panels, n0>=2048,
// write bf16 TRANSPOSED direct to Vt[B*NH, HS, T]).
// ---------------------------------------------------------------------------
template<int OUT_MODE>
__global__ __launch_bounds__(256, 2) void gemm_bt_wide(
    const short* __restrict__ A,    // [M,K] bf16
    const short* __restrict__ Bm,   // [N,K] bf16
    void* __restrict__ Cm,          // [M,N]
    short* __restrict__ Vt,         // [B*NH, HS, T] (OUT_MODE==2 only)
    int M, int N, int K)
{
    __shared__ __align__(16) short lds[24576];   // 48 KiB
    short* const Ab0 = lds;                      // [128][32] = 4096 shorts
    short* const Ab1 = lds + 4096;
    short* const Bb0 = lds + 8192;               // [256][32] = 8192 shorts
    short* const Bb1 = lds + 16384;

    // bijective XCD swizzle (gridDim.x % 8 == 0), then flat -> (bx,by)
    const int nbx = N >> 8;
    int wg = blockIdx.x;
    const int cpx = gridDim.x >> 3;
    wg = (wg & 7) * cpx + (wg >> 3);
    const int bx = wg % nbx, by = wg / nbx;
    const int m0 = by << 7, n0 = bx << 8;        // BM=128, BN=256

    const int t = threadIdx.x;
    const int w = t >> 6, lane = t & 63;         // wave w owns cols w*64..+63
    const int l16 = lane & 15, quad = lane >> 4;

    // staging: one call = 64 rows x 64B; thread -> (row = t>>2, 16B chunk t&3)
    const int rcall  = t >> 2;                   // 0..63
    const int schunk = (t & 3) ^ (rcall & 3);    // pre-swizzled source chunk
    const short* Ag = A  + (size_t)(m0 + rcall) * K + schunk * 8;
    const short* Bg = Bm + (size_t)(n0 + rcall) * K + schunk * 8;

    // frag read offsets (shorts within a [rows][32] tile), swizzled:
    // LDS[r][c] = G[r][c ^ (r&3)]  ->  global k-quad q lives at slot q^(r&3)
    int aoff[8], boff[4];
    #pragma unroll
    for (int mf = 0; mf < 8; ++mf) {
        const int ar = mf * 16 + l16;            // 0..127
        aoff[mf] = ar * 32 + ((quad ^ (ar & 3)) * 8);
    }
    #pragma unroll
    for (int nf = 0; nf < 4; ++nf) {
        const int br = w * 64 + nf * 16 + l16;   // 0..255
        boff[nf] = br * 32 + ((quad ^ (br & 3)) * 8);
    }

    f32x4 acc[8][4];
    const f32x4 zero4 = {0.f, 0.f, 0.f, 0.f};
    #pragma unroll
    for (int mf = 0; mf < 8; ++mf)
        #pragma unroll
        for (int nf = 0; nf < 4; ++nf) acc[mf][nf] = zero4;

    const int NT = K >> 5;   // 32-wide K-tiles

    // stage 64 rows (4 KB): per-wave base + HW lane*16B = linear thread*16B
    #define STW(gb, kt, ro, lb)                                                \
        load_lds16((gb) + (size_t)(ro) * K + (size_t)(kt) * 32,                \
                   (lb) + (ro) * 32 + w * 512)

    // prologue: tiles 0 and 1 fully staged -> 12 outstanding
    STW(Ag, 0, 0, Ab0); STW(Ag, 0, 64, Ab0);
    STW(Bg, 0, 0, Bb0); STW(Bg, 0, 64, Bb0);
    STW(Bg, 0, 128, Bb0); STW(Bg, 0, 192, Bb0);
    STW(Ag, 1, 0, Ab1); STW(Ag, 1, 64, Ab1);
    STW(Bg, 1, 0, Bb1); STW(Bg, 1, 64, Bb1);
    STW(Bg, 1, 128, Bb1); STW(Bg, 1, 192, Bb1);

    for (int kt = 0; kt < NT; ++kt) {
        short* Ac = (kt & 1) ? Ab1 : Ab0;
        short* Bc = (kt & 1) ? Bb1 : Bb0;

        // tile kt's 6 calls retire; tile kt+1's 6 stay in flight
        if (kt == NT - 1) asm volatile("s_waitcnt vmcnt(0)" ::: "memory");
        else              asm volatile("s_waitcnt vmcnt(6)" ::: "memory");
        __builtin_amdgcn_s_barrier();

        // all frags for this tile (8 A + 4 B ds_read_b128)
        short8 af[8], bfr[4];
        #pragma unroll
        for (int mf = 0; mf < 8; ++mf) af[mf] = *(const short8*)(Ac + aoff[mf]);
        #pragma unroll
        for (int nf = 0; nf < 4; ++nf) bfr[nf] = *(const short8*)(Bc + boff[nf]);

        // reads complete -> safe for all waves to overwrite this buffer
        asm volatile("s_waitcnt lgkmcnt(0)" ::: "memory");
        __builtin_amdgcn_s_barrier();

        // stage tile kt+2 into the just-freed buffer; rides under MFMA
        if (kt + 2 < NT) {
            STW(Ag, kt + 2, 0, Ac); STW(Ag, kt + 2, 64, Ac);
            STW(Bg, kt + 2, 0, Bc); STW(Bg, kt + 2, 64, Bc);
            STW(Bg, kt + 2, 128, Bc); STW(Bg, kt + 2, 192, Bc);
        }

        __builtin_amdgcn_s_setprio(1);
        #pragma unroll
        for (int mf = 0; mf < 8; ++mf)
            #pragma unroll
            for (int nf = 0; nf < 4; ++nf)
                acc[mf][nf] = __builtin_amdgcn_mfma_f32_16x16x32_bf16(
                    af[mf], bfr[nf], acc[mf][nf], 0, 0, 0);
        __builtin_amdgcn_s_setprio(0);
    }
    #undef STW

    if (OUT_MODE == 2 && n0 >= 2 * C_DIM) {
        // V panel -> transposed write into Vt[B*NH, HS, T]
        const int b   = m0 >> 11;
        const int tt0 = (m0 & 2047) + quad * 4;
        #pragma unroll
        for (int nf = 0; nf < 4; ++nf) {
            const int vcol = (n0 - 2 * C_DIM) + w * 64 + nf * 16 + l16;
            const int h    = vcol >> 6;          // head within b
            const int d    = vcol & 63;
            short* dcol = Vt + ((size_t)((b << 4) + h) * HS + d) * T_DIM;
            #pragma unroll
            for (int mf = 0; mf < 8; ++mf) {
                const int tt = tt0 + mf * 16;
                short4v o;
                o[0] = f2bf(acc[mf][nf][0]); o[1] = f2bf(acc[mf][nf][1]);
                o[2] = f2bf(acc[mf][nf][2]); o[3] = f2bf(acc[mf][nf][3]);
                *(short4v*)(dcol + tt) = o;
            }
        }
    } else {
        #pragma unroll
        for (int mf = 0; mf < 8; ++mf) {
            const int row_base = m0 + mf * 16 + quad * 4;
            #pragma unroll
            for (int nf = 0; nf < 4; ++nf) {
                const int col = n0 + w * 64 + nf * 16 + l16;
                #pragma unroll
                for (int r = 0; r < 4; ++r) {
                    const size_t idx = (size_t)(row_base + r) * N + col;
                    if (OUT_MODE != 0) ((short*)Cm)[idx] = f2bf(acc[mf][nf][r]);
                    else               ((float*)Cm)[idx] = acc[mf][nf][r];
                }
            }
        }
    }
}

// ---------------------------------------------------------------------------
// 8-phase-style MFMA GEMM (512 thr, 8 waves) — restored for the OUTPUT
// PROJECTION: BM=128 x BN=256, BK=64, per-wave 64x64 = acc[4][4], LDS 96 KiB
// double-buffered, 1 block/CU but grid 256 = exactly one full round with
// 8 waves/CU (verified R6/R9 config; the 256-thr wide kernel at grid 256
// leaves only 4 waves/CU with no stagger).
// ---------------------------------------------------------------------------
template<int OUT_MODE>
__global__ __launch_bounds__(512, 2) void gemm_bt_8ph(
    const short* __restrict__ A,    // [M,K] bf16
    const short* __restrict__ Bm,   // [N,K] bf16
    void* __restrict__ Cm,          // [M,N]
    short* __restrict__ Vt,         // unused unless OUT_MODE==2
    int M, int N, int K)
{
    __shared__ __align__(16) short lds[49152];   // 96 KiB

    // bijective XCD swizzle (gridDim.x % 8 == 0), then flat -> (bx,by)
    const int nbx = N >> 8;
    int wg = blockIdx.x;
    const int cpx = gridDim.x >> 3;
    wg = (wg & 7) * cpx + (wg >> 3);
    const int bx = wg % nbx, by = wg / nbx;
    const int m0 = by << 7, n0 = bx << 8;        // BM=128, BN=256

    const int t = threadIdx.x;
    const int w = t >> 6, lane = t & 63;
    const int l16 = lane & 15, quad = lane >> 4;
    const int wm = w >> 2, wn = w & 3;           // 2M x 4N waves

    const int rcall  = t >> 3;                   // 0..63
    const int schunk = (t & 7) ^ (rcall & 7);    // pre-swizzled source chunk
    const int dstoff = w * 512;                  // per-wave LDS base

    const short* Ag = A  + (size_t)(m0 + rcall) * K + schunk * 8;
    const short* Bg = Bm + (size_t)(n0 + rcall) * K + schunk * 8;

    short* const Ab0 = lds;
    short* const Ab1 = lds + 8192;
    short* const Bb0 = lds + 16384;
    short* const Bb1 = lds + 32768;

    int aoff[4][2], boff[4][2];
    #pragma unroll
    for (int mf = 0; mf < 4; ++mf) {
        const int ar = wm * 64 + mf * 16 + l16;          // 0..127
        #pragma unroll
        for (int ks = 0; ks < 2; ++ks)
            aoff[mf][ks] = ar * 64 + (((ks * 4 + quad) ^ (ar & 7)) * 8);
    }
    #pragma unroll
    for (int nf = 0; nf < 4; ++nf) {
        const int br = wn * 64 + nf * 16 + l16;          // 0..255
        #pragma unroll
        for (int ks = 0; ks < 2; ++ks)
            boff[nf][ks] = br * 64 + (((ks * 4 + quad) ^ (br & 7)) * 8);
    }

    f32x4 acc[4][4];
    const f32x4 zero4 = {0.f, 0.f, 0.f, 0.f};
    #pragma unroll
    for (int mf = 0; mf < 4; ++mf)
        #pragma unroll
        for (int nf = 0; nf < 4; ++nf) acc[mf][nf] = zero4;

    const int NT = K >> 6;   // 64-wide K-tiles

    #define ST64(gb, kt, ro, lb)                                               \
        load_lds16((gb) + (size_t)(ro) * K + (size_t)(kt) * 64,                \
                   (lb) + (ro) * 64 + dstoff)

    // prologue: t0.A (2), t0.B (4), t1.A (2)  -> 8 outstanding
    ST64(Ag, 0, 0, Ab0); ST64(Ag, 0, 64, Ab0);
    ST64(Bg, 0, 0, Bb0); ST64(Bg, 0, 64, Bb0);
    ST64(Bg, 0, 128, Bb0); ST64(Bg, 0, 192, Bb0);
    ST64(Ag, 1, 0, Ab1); ST64(Ag, 1, 64, Ab1);

    for (int kt = 0; kt < NT; ++kt) {
        short* Acur = (kt & 1) ? Ab1 : Ab0;
        short* Bcur = (kt & 1) ? Bb1 : Bb0;
        short* Bnx  = (kt & 1) ? Bb0 : Bb1;

        if (kt == NT - 1) asm volatile("s_waitcnt vmcnt(0)" ::: "memory");
        else              asm volatile("s_waitcnt vmcnt(2)" ::: "memory");
        __builtin_amdgcn_s_barrier();

        // ---- phase 0: B-frags (whole tile) + A-frags mf0,1 ----
        short8 bfr[4][2], af[2][2];
        #pragma unroll
        for (int nf = 0; nf < 4; ++nf)
            #pragma unroll
            for (int ks = 0; ks < 2; ++ks)
                bfr[nf][ks] = *(const short8*)(Bcur + boff[nf][ks]);
        #pragma unroll
        for (int mf = 0; mf < 2; ++mf)
            #pragma unroll
            for (int ks = 0; ks < 2; ++ks)
                af[mf][ks] = *(const short8*)(Acur + aoff[mf][ks]);

        if (kt + 1 < NT) { ST64(Bg, kt + 1, 0, Bnx); ST64(Bg, kt + 1, 64, Bnx); }

        __builtin_amdgcn_s_barrier();
        __builtin_amdgcn_s_setprio(1);
        #pragma unroll
        for (int mf = 0; mf < 2; ++mf)
            #pragma unroll
            for (int nf = 0; nf < 4; ++nf)
                #pragma unroll
                for (int ks = 0; ks < 2; ++ks)
                    acc[mf][nf] = __builtin_amdgcn_mfma_f32_16x16x32_bf16(
                        af[mf][ks], bfr[nf][ks], acc[mf][nf], 0, 0, 0);
        __builtin_amdgcn_s_setprio(0);
        __builtin_amdgcn_s_barrier();

        // ---- phase 1: A-frags mf2,3 ----
        short8 af2[2][2];
        #pragma unroll
        for (int mf = 0; mf < 2; ++mf)
            #pragma unroll
            for (int ks = 0; ks < 2; ++ks)
                af2[mf][ks] = *(const short8*)(Acur + aoff[2 + mf][ks]);

        if (kt + 1 < NT) { ST64(Bg, kt + 1, 128, Bnx); ST64(Bg, kt + 1, 192, Bnx); }

        __builtin_amdgcn_s_barrier();
        __builtin_amdgcn_s_setprio(1);
        #pragma unroll
        for (int mf = 0; mf < 2; ++mf)
            #pragma unroll
            for (int nf = 0; nf < 4; ++nf)
                #pragma unroll
                for (int ks = 0; ks < 2; ++ks)
                    acc[2 + mf][nf] = __builtin_amdgcn_mfma_f32_16x16x32_bf16(
                        af2[mf][ks], bfr[nf][ks], acc[2 + mf][nf], 0, 0, 0);
        __builtin_amdgcn_s_setprio(0);
        __builtin_amdgcn_s_barrier();

        // tail: just-freed A buffer -> prefetch (t+2).A
        if (kt + 2 < NT) {
            short* Aw = (kt & 1) ? Ab1 : Ab0;
            ST64(Ag, kt + 2, 0, Aw); ST64(Ag, kt + 2, 64, Aw);
        }
    }
    #undef ST64

    #pragma unroll
    for (int mf = 0; mf < 4; ++mf) {
        const int row_base = m0 + wm * 64 + mf * 16 + quad * 4;
        #pragma unroll
        for (int nf = 0; nf < 4; ++nf) {
            const int col = n0 + wn * 64 + nf * 16 + l16;
            #pragma unroll
            for (int r = 0; r < 4; ++r) {
                const size_t idx = (size_t)(row_base + r) * N + col;
                if (OUT_MODE != 0) ((short*)Cm)[idx] = f2bf(acc[mf][nf][r]);
                else               ((float*)Cm)[idx] = acc[mf][nf][r];
            }
        }
    }
}

// ---------------------------------------------------------------------------
// Flash attention v9 (frozen): QSUB=2, 4 blocks/CU, head-locality XCD
// swizzle, double-buffered K/V LDS with reg prefetch (1 barrier/tile).
//  - [64][72] padded LDS rows; Q pre-scaled by log2(e)/8; l via ones-MFMA.
// S^T trick: A=K-frag, B=Q-frag -> D[key][q]; K rows permuted kappa^-1.
// ---------------------------------------------------------------------------
#define QSUB 2

__global__ __launch_bounds__(256, 4) void attn_mfma3(
    const short* __restrict__ Qb,    // [B,T,QKV_LD], Q cols (pre-scaled)
    const short* __restrict__ Kb,    // [B,T,QKV_LD], K cols
    const short* __restrict__ Vt,    // [B*NH, HS, T]
    short* __restrict__ O)           // [B,T,C] bf16
{
    const int bid  = blockIdx.x;
    const int slot = bid >> 3;
    const int head = ((bid & 7) << 3) + (slot >> 4);
    const int i0   = (slot & 15) * (64 * QSUB);
    const int b = head >> 4, h = head & 15;

    const int t    = threadIdx.x;
    const int w    = t >> 6;
    const int lane = t & 63;
    const int l16  = lane & 15;
    const int quad = lane >> 4;

    __shared__ short Ks[2][64][72];     // [buf][perm key][dim]
    __shared__ short Vts[2][64][72];    // [buf][dim][key]

    short8 qf[QSUB][2];
    #pragma unroll
    for (int sub = 0; sub < QSUB; ++sub) {
        const short* qrow = Qb
            + ((size_t)(b * T_DIM) + i0 + sub * 64 + w * 16 + l16) * QKV_LD + h * HS;
        qf[sub][0] = *(const short8*)(qrow + quad * 8);
        qf[sub][1] = *(const short8*)(qrow + 32 + quad * 8);
    }

    short8 onesv;
    #pragma unroll
    for (int j = 0; j < 8; ++j) onesv[j] = (short)0x3F80;

    const f32x4 zero4 = {0.f, 0.f, 0.f, 0.f};
    f32x4 oacc[QSUB][4];
    f32x4 lacc[QSUB];
    #pragma unroll
    for (int sub = 0; sub < QSUB; ++sub) {
        #pragma unroll
        for (int dg = 0; dg < 4; ++dg) oacc[sub][dg] = zero4;
        lacc[sub] = zero4;
    }

    const int sr = t >> 2;
    const int sc = (t & 3) * 16;
    const int krow = (sr & 32) | ((sr & 4) << 2) | ((sr & 24) >> 1) | (sr & 3);
    const short* kgbase = Kb + (size_t)(b * T_DIM) * QKV_LD + h * HS;
    const short* vgbase = Vt + ((size_t)head * HS + sr) * T_DIM;

    short8 kr0, kr1, vr0, vr1;
    {
        const short* kp = kgbase + (size_t)sr * QKV_LD + sc;
        kr0 = *(const short8*)kp;
        kr1 = *(const short8*)(kp + 8);
        vr0 = *(const short8*)(vgbase + sc);
        vr1 = *(const short8*)(vgbase + sc + 8);
    }

    const int NT = T_DIM / 64;
    for (int kt2 = 0; kt2 < NT; ++kt2) {
        const int buf = kt2 & 1;

        *(short8*)&Ks[buf][krow][sc]     = kr0;
        *(short8*)&Ks[buf][krow][sc + 8] = kr1;
        *(short8*)&Vts[buf][sr][sc]      = vr0;
        *(short8*)&Vts[buf][sr][sc + 8]  = vr1;
        __syncthreads();

        if (kt2 + 1 < NT) {
            const int j1 = (kt2 + 1) * 64;
            const short* kp = kgbase + (size_t)(j1 + sr) * QKV_LD + sc;
            kr0 = *(const short8*)kp;
            kr1 = *(const short8*)(kp + 8);
            const short* vp = vgbase + j1;
            vr0 = *(const short8*)(vp + sc);
            vr1 = *(const short8*)(vp + sc + 8);
        }

        short8 ka[4][2], va[4][2];
        #pragma unroll
        for (int kt = 0; kt < 4; ++kt) {
            ka[kt][0] = *(const short8*)&Ks[buf][kt * 16 + l16][quad * 8];
            ka[kt][1] = *(const short8*)&Ks[buf][kt * 16 + l16][32 + quad * 8];
            va[kt][0] = *(const short8*)&Vts[buf][kt * 16 + l16][quad * 8];
            va[kt][1] = *(const short8*)&Vts[buf][kt * 16 + l16][32 + quad * 8];
        }

        #pragma unroll
        for (int sub = 0; sub < QSUB; ++sub) {
            f32x4 s[4];
            #pragma unroll
            for (int kt = 0; kt < 4; ++kt) {
                f32x4 acc = zero4;
                acc = __builtin_amdgcn_mfma_f32_16x16x32_bf16(ka[kt][0], qf[sub][0], acc, 0, 0, 0);
                acc = __builtin_amdgcn_mfma_f32_16x16x32_bf16(ka[kt][1], qf[sub][1], acc, 0, 0, 0);
                s[kt] = acc;
            }

            short8 pa[2];
            #pragma unroll
            for (int hh = 0; hh < 2; ++hh) {
                #pragma unroll
                for (int c = 0; c < 2; ++c) {
                    f32x4 sv = s[2 * hh + c];
                    #pragma unroll
                    for (int r = 0; r < 4; ++r) {
                        float p = __builtin_amdgcn_exp2f(sv[r]);
                        pa[hh][c * 4 + r] = f2bf(p);
                    }
                }
            }

            lacc[sub] = __builtin_amdgcn_mfma_f32_16x16x32_bf16(pa[0], onesv, lacc[sub], 0, 0, 0);
            lacc[sub] = __builtin_amdgcn_mfma_f32_16x16x32_bf16(pa[1], onesv, lacc[sub], 0, 0, 0);

            #pragma unroll
            for (int dg = 0; dg < 4; ++dg) {
                oacc[sub][dg] = __builtin_amdgcn_mfma_f32_16x16x32_bf16(pa[0], va[dg][0], oacc[sub][dg], 0, 0, 0);
                oacc[sub][dg] = __builtin_amdgcn_mfma_f32_16x16x32_bf16(pa[1], va[dg][1], oacc[sub][dg], 0, 0, 0);
            }
        }
    }

    #pragma unroll
    for (int sub = 0; sub < QSUB; ++sub) {
        float linv[4];
        #pragma unroll
        for (int r = 0; r < 4; ++r) linv[r] = 1.0f / lacc[sub][r];

        #pragma unroll
        for (int r = 0; r < 4; ++r) {
            short* orow = O + ((size_t)(b * T_DIM) + i0 + sub * 64 + w * 16 + quad * 4 + r) * C_DIM + h * HS;
            #pragma unroll
            for (int dg = 0; dg < 4; ++dg)
                orow[dg * 16 + l16] = f2bf(oacc[sub][dg][r] * linv[r]);
        }
    }
}

// ---------------------------------------------------------------------------
// ws layout (bytes), NB = 2*M*C = 16.8MB, WB = 2*C*C = 2.1MB:
//   [0]      xb bf16 (reused as Ob after QKV gemm)
//   [NB]     QKVb bf16 [M,3C]  (3*NB; V cols unwritten — V goes direct to Vt)
//   [4NB]    Vt bf16 [B*NH,HS,T]
//   [5NB]    W3b (Wq|Wk|Wv rows, 3*WB) | Wob (WB)      total 92.4MB
// ---------------------------------------------------------------------------
extern "C" void kernel_launch(void* const* d_in, const int* in_sizes, int n_in,
                              void* d_out, int out_size, void* d_ws, size_t ws_size,
                              hipStream_t stream) {
    const float* x  = (const float*)d_in[0];
    const float* Wk = (const float*)d_in[1];
    const float* Wq = (const float*)d_in[2];
    const float* Wv = (const float*)d_in[3];
    const float* Wo = (const float*)d_in[4];
    float* out = (float*)d_out;

    const int M = B_DIM * T_DIM;                       // 8192
    const size_t NE = (size_t)M * C_DIM;               // 8.4M
    const size_t NB = 2 * NE;                          // bytes
    const size_t WB = (size_t)2 * C_DIM * C_DIM;

    char* ws = (char*)d_ws;
    short* xb   = (short*)(ws);
    short* Ob   = xb;                                  // reuse after QKV gemm
    short* QKVb = (short*)(ws + NB);
    short* Vtb  = (short*)(ws + 4 * NB);
    short* W3b  = (short*)(ws + 5 * NB);               // [3C, C] rows: Wq|Wk|Wv (then Wob)
    short* Wob  = (short*)(ws + 5 * NB + 3 * WB);

    // all casts in one launch (Wq pre-scaled by log2(e)/8)
    cast_all<<<dim3(XBLK + 4 * WBLK), 256, 0, stream>>>(
        x, Wq, Wk, Wv, Wo, xb, W3b);

    // fused QKV projection + V-transpose epilogue (wide-wave, grid 768)
    gemm_bt_wide<2><<<dim3((QKV_LD / 256) * (M / 128)), 256, 0, stream>>>(
        xb, W3b, QKVb, Vtb, M, QKV_LD, C_DIM);

    // attention (2x q-merge, 1024 blocks = 4 blocks/CU, head-locality swizzle)
    attn_mfma3<<<dim3(T_DIM / (64 * QSUB) * B_DIM * NHEAD), 256, 0, stream>>>(
        QKVb, QKVb + C_DIM, Vtb, Ob);

    // output projection (8ph 512-thr, grid 256 = one full round, fp32 out)
    gemm_bt_8ph<0><<<dim3((C_DIM / 256) * (M / 128)), 512, 0, stream>>>(
        Ob, Wob, out, nullptr, M, C_DIM, C_DIM);
}

// Round 12
// 247.051 us; speedup vs baseline: 1.0314x; 1.0100x over previous
//
#include <hip/hip_runtime.h>
#include <hip/hip_bf16.h>
#include <cstddef>
#include <cstdint>

// Problem constants: B=4, T=2048, C=1024, NH=16, hs=64, M = B*T = 8192
#define B_DIM 4
#define T_DIM 2048
#define C_DIM 1024
#define NHEAD 16
#define HS    64
#define QKV_LD 3072   // fused QKV row stride (3*C)

// log2(e)/8 : folded into the Wq bf16 cast so QK^T emerges in exp2-domain.
#define QSCALE 0.18033688011112042f

typedef __attribute__((ext_vector_type(8))) short short8;   // 8 bf16 (MFMA A/B frag)
typedef __attribute__((ext_vector_type(4))) short short4v;  // 4 bf16 (8B store)
typedef __attribute__((ext_vector_type(4))) float f32x4;    // MFMA C/D frag

__device__ __forceinline__ short f2bf(float x) {
    __hip_bfloat16 b = __float2bfloat16(x);   // RNE
    return *reinterpret_cast<short*>(&b);
}

// async global->LDS, 16B per lane; LDS dest is wave-uniform base + lane*16.
__device__ __forceinline__ void load_lds16(const void* g, void* l) {
    __builtin_amdgcn_global_load_lds(
        (const __attribute__((address_space(1))) void*)(g),
        (__attribute__((address_space(3))) void*)(l),
        16, 0, 0);
}

// ---------------------------------------------------------------------------
// Fused cast: x (4096 blocks) + 4 weights (4 x 512 blocks) in ONE launch.
// Weights go to one contiguous bf16 region (Wq|Wk|Wv|Wo); Wq gets QSCALE.
// ---------------------------------------------------------------------------
#define XBLK 4096   // (M*C/8)/256
#define WBLK 512    // (C*C/8)/256

__global__ __launch_bounds__(256) void cast_all(
    const float* __restrict__ x,
    const float* __restrict__ wq, const float* __restrict__ wk,
    const float* __restrict__ wv, const float* __restrict__ wo,
    short* __restrict__ xb, short* __restrict__ wout)
{
    const int bid = blockIdx.x;
    const float* in;
    short* out;
    float scale;
    int i;
    if (bid < XBLK) {
        i = bid * 256 + threadIdx.x;
        in = x; out = xb; scale = 1.0f;
    } else {
        const int r = bid - XBLK;
        const int sel = r >> 9;                  // /WBLK
        i = (r & (WBLK - 1)) * 256 + threadIdx.x;
        in  = (sel == 0) ? wq : (sel == 1) ? wk : (sel == 2) ? wv : wo;
        out = wout + (size_t)sel * (WBLK * 256 * 8);
        scale = (sel == 0) ? QSCALE : 1.0f;
    }
    const float4* p = (const float4*)in + (size_t)i * 2;
    float4 a = p[0], b = p[1];
    short8 o;
    o[0]=f2bf(a.x*scale); o[1]=f2bf(a.y*scale); o[2]=f2bf(a.z*scale); o[3]=f2bf(a.w*scale);
    o[4]=f2bf(b.x*scale); o[5]=f2bf(b.y*scale); o[6]=f2bf(b.z*scale); o[7]=f2bf(b.w*scale);
    *((short8*)out + i) = o;
}

// ---------------------------------------------------------------------------
// GEMM "wide-wave" v2 (QKV): BM=128 x BN=256, BK=32, 256 threads = 4 waves,
// each wave owns 128x64 (acc[8][4]). LDS 48 KiB double-buffered.
// R12 restructure for 3 blocks/CU: no barrier between frag reads and MFMA
// (compiler interleaves them -> af[mf] dies after its 4 MFMAs, peak VGPR
// ~165 fits launch_bounds(256,3)); stage tile t+2 AFTER the MFMAs, giving
// its 6 calls a full iteration to land before tile t+2's vmcnt(6) gate.
// Per tile: vmcnt(6) -> bar -> {12 ds_read ||| 32 MFMA} -> bar -> stage t+2.
// Grid 768 = exactly 3 blocks/CU (3 full rounds).
// OUT_MODE: 0 = fp32 out; 2 = QKV fused epilogue (V panels, n0>=2048,
// write bf16 TRANSPOSED direct to Vt[B*NH, HS, T]).
// ---------------------------------------------------------------------------
template<int OUT_MODE>
__global__ __launch_bounds__(256, 3) void gemm_bt_wide(
    const short* __restrict__ A,    // [M,K] bf16
    const short* __restrict__ Bm,   // [N,K] bf16
    void* __restrict__ Cm,          // [M,N]
    short* __restrict__ Vt,         // [B*NH, HS, T] (OUT_MODE==2 only)
    int M, int N, int K)
{
    __shared__ __align__(16) short lds[24576];   // 48 KiB
    short* const Ab0 = lds;                      // [128][32] = 4096 shorts
    short* const Ab1 = lds + 4096;
    short* const Bb0 = lds + 8192;               // [256][32] = 8192 shorts
    short* const Bb1 = lds + 16384;

    // bijective XCD swizzle (gridDim.x % 8 == 0), then flat -> (bx,by)
    const int nbx = N >> 8;
    int wg = blockIdx.x;
    const int cpx = gridDim.x >> 3;
    wg = (wg & 7) * cpx + (wg >> 3);
    const int bx = wg % nbx, by = wg / nbx;
    const int m0 = by << 7, n0 = bx << 8;        // BM=128, BN=256

    const int t = threadIdx.x;
    const int w = t >> 6, lane = t & 63;         // wave w owns cols w*64..+63
    const int l16 = lane & 15, quad = lane >> 4;

    // staging: one call = 64 rows x 64B; thread -> (row = t>>2, 16B chunk t&3)
    const int rcall  = t >> 2;                   // 0..63
    const int schunk = (t & 3) ^ (rcall & 3);    // pre-swizzled source chunk
    const short* Ag = A  + (size_t)(m0 + rcall) * K + schunk * 8;
    const short* Bg = Bm + (size_t)(n0 + rcall) * K + schunk * 8;

    // frag read offsets (shorts within a [rows][32] tile), swizzled:
    // LDS[r][c] = G[r][c ^ (r&3)]  ->  global k-quad q lives at slot q^(r&3)
    int aoff[8], boff[4];
    #pragma unroll
    for (int mf = 0; mf < 8; ++mf) {
        const int ar = mf * 16 + l16;            // 0..127
        aoff[mf] = ar * 32 + ((quad ^ (ar & 3)) * 8);
    }
    #pragma unroll
    for (int nf = 0; nf < 4; ++nf) {
        const int br = w * 64 + nf * 16 + l16;   // 0..255
        boff[nf] = br * 32 + ((quad ^ (br & 3)) * 8);
    }

    f32x4 acc[8][4];
    const f32x4 zero4 = {0.f, 0.f, 0.f, 0.f};
    #pragma unroll
    for (int mf = 0; mf < 8; ++mf)
        #pragma unroll
        for (int nf = 0; nf < 4; ++nf) acc[mf][nf] = zero4;

    const int NT = K >> 5;   // 32-wide K-tiles

    // stage 64 rows (4 KB): per-wave base + HW lane*16B = linear thread*16B
    #define STW(gb, kt, ro, lb)                                                \
        load_lds16((gb) + (size_t)(ro) * K + (size_t)(kt) * 32,                \
                   (lb) + (ro) * 32 + w * 512)

    // prologue: tiles 0 and 1 fully staged -> 12 outstanding
    STW(Ag, 0, 0, Ab0); STW(Ag, 0, 64, Ab0);
    STW(Bg, 0, 0, Bb0); STW(Bg, 0, 64, Bb0);
    STW(Bg, 0, 128, Bb0); STW(Bg, 0, 192, Bb0);
    STW(Ag, 1, 0, Ab1); STW(Ag, 1, 64, Ab1);
    STW(Bg, 1, 0, Bb1); STW(Bg, 1, 64, Bb1);
    STW(Bg, 1, 128, Bb1); STW(Bg, 1, 192, Bb1);

    for (int kt = 0; kt < NT; ++kt) {
        short* Ac = (kt & 1) ? Ab1 : Ab0;
        short* Bc = (kt & 1) ? Bb1 : Bb0;

        // tile kt's 6 calls retire; tile kt+1's 6 stay in flight
        if (kt == NT - 1) asm volatile("s_waitcnt vmcnt(0)" ::: "memory");
        else              asm volatile("s_waitcnt vmcnt(6)" ::: "memory");
        __builtin_amdgcn_s_barrier();

        // frag reads + MFMAs in ONE schedulable region: compiler interleaves
        // (ds_read af[mf] -> 4 MFMAs -> af[mf] dies), keeping VGPR ~165.
        short8 bfr[4];
        #pragma unroll
        for (int nf = 0; nf < 4; ++nf) bfr[nf] = *(const short8*)(Bc + boff[nf]);

        __builtin_amdgcn_s_setprio(1);
        #pragma unroll
        for (int mf = 0; mf < 8; ++mf) {
            const short8 af = *(const short8*)(Ac + aoff[mf]);
            #pragma unroll
            for (int nf = 0; nf < 4; ++nf)
                acc[mf][nf] = __builtin_amdgcn_mfma_f32_16x16x32_bf16(
                    af, bfr[nf], acc[mf][nf], 0, 0, 0);
        }
        __builtin_amdgcn_s_setprio(0);

        // all waves' reads of this buffer are complete (consumed by MFMA)
        __builtin_amdgcn_s_barrier();

        // stage tile kt+2 into the just-freed buffer; has all of tile kt+1
        // to land before tile kt+2's vmcnt gate.
        if (kt + 2 < NT) {
            STW(Ag, kt + 2, 0, Ac); STW(Ag, kt + 2, 64, Ac);
            STW(Bg, kt + 2, 0, Bc); STW(Bg, kt + 2, 64, Bc);
            STW(Bg, kt + 2, 128, Bc); STW(Bg, kt + 2, 192, Bc);
        }
    }
    #undef STW

    if (OUT_MODE == 2 && n0 >= 2 * C_DIM) {
        // V panel -> transposed write into Vt[B*NH, HS, T]
        const int b   = m0 >> 11;
        const int tt0 = (m0 & 2047) + quad * 4;
        #pragma unroll
        for (int nf = 0; nf < 4; ++nf) {
            const int vcol = (n0 - 2 * C_DIM) + w * 64 + nf * 16 + l16;
            const int h    = vcol >> 6;          // head within b
            const int d    = vcol & 63;
            short* dcol = Vt + ((size_t)((b << 4) + h) * HS + d) * T_DIM;
            #pragma unroll
            for (int mf = 0; mf < 8; ++mf) {
                const int tt = tt0 + mf * 16;
                short4v o;
                o[0] = f2bf(acc[mf][nf][0]); o[1] = f2bf(acc[mf][nf][1]);
                o[2] = f2bf(acc[mf][nf][2]); o[3] = f2bf(acc[mf][nf][3]);
                *(short4v*)(dcol + tt) = o;
            }
        }
    } else {
        #pragma unroll
        for (int mf = 0; mf < 8; ++mf) {
            const int row_base = m0 + mf * 16 + quad * 4;
            #pragma unroll
            for (int nf = 0; nf < 4; ++nf) {
                const int col = n0 + w * 64 + nf * 16 + l16;
                #pragma unroll
                for (int r = 0; r < 4; ++r) {
                    const size_t idx = (size_t)(row_base + r) * N + col;
                    if (OUT_MODE != 0) ((short*)Cm)[idx] = f2bf(acc[mf][nf][r]);
                    else               ((float*)Cm)[idx] = acc[mf][nf][r];
                }
            }
        }
    }
}

// ---------------------------------------------------------------------------
// 8-phase-style MFMA GEMM (512 thr, 8 waves) — OUTPUT PROJECTION (frozen):
// BM=128 x BN=256, BK=64, per-wave 64x64 = acc[4][4], LDS 96 KiB
// double-buffered, grid 256 = exactly one full round with 8 waves/CU.
// ---------------------------------------------------------------------------
template<int OUT_MODE>
__global__ __launch_bounds__(512, 2) void gemm_bt_8ph(
    const short* __restrict__ A,    // [M,K] bf16
    const short* __restrict__ Bm,   // [N,K] bf16
    void* __restrict__ Cm,          // [M,N]
    short* __restrict__ Vt,         // unused unless OUT_MODE==2
    int M, int N, int K)
{
    __shared__ __align__(16) short lds[49152];   // 96 KiB

    // bijective XCD swizzle (gridDim.x % 8 == 0), then flat -> (bx,by)
    const int nbx = N >> 8;
    int wg = blockIdx.x;
    const int cpx = gridDim.x >> 3;
    wg = (wg & 7) * cpx + (wg >> 3);
    const int bx = wg % nbx, by = wg / nbx;
    const int m0 = by << 7, n0 = bx << 8;        // BM=128, BN=256

    const int t = threadIdx.x;
    const int w = t >> 6, lane = t & 63;
    const int l16 = lane & 15, quad = lane >> 4;
    const int wm = w >> 2, wn = w & 3;           // 2M x 4N waves

    const int rcall  = t >> 3;                   // 0..63
    const int schunk = (t & 7) ^ (rcall & 7);    // pre-swizzled source chunk
    const int dstoff = w * 512;                  // per-wave LDS base

    const short* Ag = A  + (size_t)(m0 + rcall) * K + schunk * 8;
    const short* Bg = Bm + (size_t)(n0 + rcall) * K + schunk * 8;

    short* const Ab0 = lds;
    short* const Ab1 = lds + 8192;
    short* const Bb0 = lds + 16384;
    short* const Bb1 = lds + 32768;

    int aoff[4][2], boff[4][2];
    #pragma unroll
    for (int mf = 0; mf < 4; ++mf) {
        const int ar = wm * 64 + mf * 16 + l16;          // 0..127
        #pragma unroll
        for (int ks = 0; ks < 2; ++ks)
            aoff[mf][ks] = ar * 64 + (((ks * 4 + quad) ^ (ar & 7)) * 8);
    }
    #pragma unroll
    for (int nf = 0; nf < 4; ++nf) {
        const int br = wn * 64 + nf * 16 + l16;          // 0..255
        #pragma unroll
        for (int ks = 0; ks < 2; ++ks)
            boff[nf][ks] = br * 64 + (((ks * 4 + quad) ^ (br & 7)) * 8);
    }

    f32x4 acc[4][4];
    const f32x4 zero4 = {0.f, 0.f, 0.f, 0.f};
    #pragma unroll
    for (int mf = 0; mf < 4; ++mf)
        #pragma unroll
        for (int nf = 0; nf < 4; ++nf) acc[mf][nf] = zero4;

    const int NT = K >> 6;   // 64-wide K-tiles

    #define ST64(gb, kt, ro, lb)                                               \
        load_lds16((gb) + (size_t)(ro) * K + (size_t)(kt) * 64,                \
                   (lb) + (ro) * 64 + dstoff)

    // prologue: t0.A (2), t0.B (4), t1.A (2)  -> 8 outstanding
    ST64(Ag, 0, 0, Ab0); ST64(Ag, 0, 64, Ab0);
    ST64(Bg, 0, 0, Bb0); ST64(Bg, 0, 64, Bb0);
    ST64(Bg, 0, 128, Bb0); ST64(Bg, 0, 192, Bb0);
    ST64(Ag, 1, 0, Ab1); ST64(Ag, 1, 64, Ab1);

    for (int kt = 0; kt < NT; ++kt) {
        short* Acur = (kt & 1) ? Ab1 : Ab0;
        short* Bcur = (kt & 1) ? Bb1 : Bb0;
        short* Bnx  = (kt & 1) ? Bb0 : Bb1;

        if (kt == NT - 1) asm volatile("s_waitcnt vmcnt(0)" ::: "memory");
        else              asm volatile("s_waitcnt vmcnt(2)" ::: "memory");
        __builtin_amdgcn_s_barrier();

        // ---- phase 0: B-frags (whole tile) + A-frags mf0,1 ----
        short8 bfr[4][2], af[2][2];
        #pragma unroll
        for (int nf = 0; nf < 4; ++nf)
            #pragma unroll
            for (int ks = 0; ks < 2; ++ks)
                bfr[nf][ks] = *(const short8*)(Bcur + boff[nf][ks]);
        #pragma unroll
        for (int mf = 0; mf < 2; ++mf)
            #pragma unroll
            for (int ks = 0; ks < 2; ++ks)
                af[mf][ks] = *(const short8*)(Acur + aoff[mf][ks]);

        if (kt + 1 < NT) { ST64(Bg, kt + 1, 0, Bnx); ST64(Bg, kt + 1, 64, Bnx); }

        __builtin_amdgcn_s_barrier();
        __builtin_amdgcn_s_setprio(1);
        #pragma unroll
        for (int mf = 0; mf < 2; ++mf)
            #pragma unroll
            for (int nf = 0; nf < 4; ++nf)
                #pragma unroll
                for (int ks = 0; ks < 2; ++ks)
                    acc[mf][nf] = __builtin_amdgcn_mfma_f32_16x16x32_bf16(
                        af[mf][ks], bfr[nf][ks], acc[mf][nf], 0, 0, 0);
        __builtin_amdgcn_s_setprio(0);
        __builtin_amdgcn_s_barrier();

        // ---- phase 1: A-frags mf2,3 ----
        short8 af2[2][2];
        #pragma unroll
        for (int mf = 0; mf < 2; ++mf)
            #pragma unroll
            for (int ks = 0; ks < 2; ++ks)
                af2[mf][ks] = *(const short8*)(Acur + aoff[2 + mf][ks]);

        if (kt + 1 < NT) { ST64(Bg, kt + 1, 128, Bnx); ST64(Bg, kt + 1, 192, Bnx); }

        __builtin_amdgcn_s_barrier();
        __builtin_amdgcn_s_setprio(1);
        #pragma unroll
        for (int mf = 0; mf < 2; ++mf)
            #pragma unroll
            for (int nf = 0; nf < 4; ++nf)
                #pragma unroll
                for (int ks = 0; ks < 2; ++ks)
                    acc[2 + mf][nf] = __builtin_amdgcn_mfma_f32_16x16x32_bf16(
                        af2[mf][ks], bfr[nf][ks], acc[2 + mf][nf], 0, 0, 0);
        __builtin_amdgcn_s_setprio(0);
        __builtin_amdgcn_s_barrier();

        // tail: just-freed A buffer -> prefetch (t+2).A
        if (kt + 2 < NT) {
            short* Aw = (kt & 1) ? Ab1 : Ab0;
            ST64(Ag, kt + 2, 0, Aw); ST64(Ag, kt + 2, 64, Aw);
        }
    }
    #undef ST64

    #pragma unroll
    for (int mf = 0; mf < 4; ++mf) {
        const int row_base = m0 + wm * 64 + mf * 16 + quad * 4;
        #pragma unroll
        for (int nf = 0; nf < 4; ++nf) {
            const int col = n0 + wn * 64 + nf * 16 + l16;
            #pragma unroll
            for (int r = 0; r < 4; ++r) {
                const size_t idx = (size_t)(row_base + r) * N + col;
                if (OUT_MODE != 0) ((short*)Cm)[idx] = f2bf(acc[mf][nf][r]);
                else               ((float*)Cm)[idx] = acc[mf][nf][r];
            }
        }
    }
}

// ---------------------------------------------------------------------------
// Flash attention v9 (frozen): QSUB=2, 4 blocks/CU, head-locality XCD
// swizzle, double-buffered K/V LDS with reg prefetch (1 barrier/tile).
//  - [64][72] padded LDS rows; Q pre-scaled by log2(e)/8; l via ones-MFMA.
// S^T trick: A=K-frag, B=Q-frag -> D[key][q]; K rows permuted kappa^-1.
// ---------------------------------------------------------------------------
#define QSUB 2

__global__ __launch_bounds__(256, 4) void attn_mfma3(
    const short* __restrict__ Qb,    // [B,T,QKV_LD], Q cols (pre-scaled)
    const short* __restrict__ Kb,    // [B,T,QKV_LD], K cols
    const short* __restrict__ Vt,    // [B*NH, HS, T]
    short* __restrict__ O)           // [B,T,C] bf16
{
    const int bid  = blockIdx.x;
    const int slot = bid >> 3;
    const int head = ((bid & 7) << 3) + (slot >> 4);
    const int i0   = (slot & 15) * (64 * QSUB);
    const int b = head >> 4, h = head & 15;

    const int t    = threadIdx.x;
    const int w    = t >> 6;
    const int lane = t & 63;
    const int l16  = lane & 15;
    const int quad = lane >> 4;

    __shared__ short Ks[2][64][72];     // [buf][perm key][dim]
    __shared__ short Vts[2][64][72];    // [buf][dim][key]

    short8 qf[QSUB][2];
    #pragma unroll
    for (int sub = 0; sub < QSUB; ++sub) {
        const short* qrow = Qb
            + ((size_t)(b * T_DIM) + i0 + sub * 64 + w * 16 + l16) * QKV_LD + h * HS;
        qf[sub][0] = *(const short8*)(qrow + quad * 8);
        qf[sub][1] = *(const short8*)(qrow + 32 + quad * 8);
    }

    short8 onesv;
    #pragma unroll
    for (int j = 0; j < 8; ++j) onesv[j] = (short)0x3F80;

    const f32x4 zero4 = {0.f, 0.f, 0.f, 0.f};
    f32x4 oacc[QSUB][4];
    f32x4 lacc[QSUB];
    #pragma unroll
    for (int sub = 0; sub < QSUB; ++sub) {
        #pragma unroll
        for (int dg = 0; dg < 4; ++dg) oacc[sub][dg] = zero4;
        lacc[sub] = zero4;
    }

    const int sr = t >> 2;
    const int sc = (t & 3) * 16;
    const int krow = (sr & 32) | ((sr & 4) << 2) | ((sr & 24) >> 1) | (sr & 3);
    const short* kgbase = Kb + (size_t)(b * T_DIM) * QKV_LD + h * HS;
    const short* vgbase = Vt + ((size_t)head * HS + sr) * T_DIM;

    short8 kr0, kr1, vr0, vr1;
    {
        const short* kp = kgbase + (size_t)sr * QKV_LD + sc;
        kr0 = *(const short8*)kp;
        kr1 = *(const short8*)(kp + 8);
        vr0 = *(const short8*)(vgbase + sc);
        vr1 = *(const short8*)(vgbase + sc + 8);
    }

    const int NT = T_DIM / 64;
    for (int kt2 = 0; kt2 < NT; ++kt2) {
        const int buf = kt2 & 1;

        *(short8*)&Ks[buf][krow][sc]     = kr0;
        *(short8*)&Ks[buf][krow][sc + 8] = kr1;
        *(short8*)&Vts[buf][sr][sc]      = vr0;
        *(short8*)&Vts[buf][sr][sc + 8]  = vr1;
        __syncthreads();

        if (kt2 + 1 < NT) {
            const int j1 = (kt2 + 1) * 64;
            const short* kp = kgbase + (size_t)(j1 + sr) * QKV_LD + sc;
            kr0 = *(const short8*)kp;
            kr1 = *(const short8*)(kp + 8);
            const short* vp = vgbase + j1;
            vr0 = *(const short8*)(vp + sc);
            vr1 = *(const short8*)(vp + sc + 8);
        }

        short8 ka[4][2], va[4][2];
        #pragma unroll
        for (int kt = 0; kt < 4; ++kt) {
            ka[kt][0] = *(const short8*)&Ks[buf][kt * 16 + l16][quad * 8];
            ka[kt][1] = *(const short8*)&Ks[buf][kt * 16 + l16][32 + quad * 8];
            va[kt][0] = *(const short8*)&Vts[buf][kt * 16 + l16][quad * 8];
            va[kt][1] = *(const short8*)&Vts[buf][kt * 16 + l16][32 + quad * 8];
        }

        #pragma unroll
        for (int sub = 0; sub < QSUB; ++sub) {
            f32x4 s[4];
            #pragma unroll
            for (int kt = 0; kt < 4; ++kt) {
                f32x4 acc = zero4;
                acc = __builtin_amdgcn_mfma_f32_16x16x32_bf16(ka[kt][0], qf[sub][0], acc, 0, 0, 0);
                acc = __builtin_amdgcn_mfma_f32_16x16x32_bf16(ka[kt][1], qf[sub][1], acc, 0, 0, 0);
                s[kt] = acc;
            }

            short8 pa[2];
            #pragma unroll
            for (int hh = 0; hh < 2; ++hh) {
                #pragma unroll
                for (int c = 0; c < 2; ++c) {
                    f32x4 sv = s[2 * hh + c];
                    #pragma unroll
                    for (int r = 0; r < 4; ++r) {
                        float p = __builtin_amdgcn_exp2f(sv[r]);
                        pa[hh][c * 4 + r] = f2bf(p);
                    }
                }
            }

            lacc[sub] = __builtin_amdgcn_mfma_f32_16x16x32_bf16(pa[0], onesv, lacc[sub], 0, 0, 0);
            lacc[sub] = __builtin_amdgcn_mfma_f32_16x16x32_bf16(pa[1], onesv, lacc[sub], 0, 0, 0);

            #pragma unroll
            for (int dg = 0; dg < 4; ++dg) {
                oacc[sub][dg] = __builtin_amdgcn_mfma_f32_16x16x32_bf16(pa[0], va[dg][0], oacc[sub][dg], 0, 0, 0);
                oacc[sub][dg] = __builtin_amdgcn_mfma_f32_16x16x32_bf16(pa[1], va[dg][1], oacc[sub][dg], 0, 0, 0);
            }
        }
    }

    #pragma unroll
    for (int sub = 0; sub < QSUB; ++sub) {
        float linv[4];
        #pragma unroll
        for (int r = 0; r < 4; ++r) linv[r] = 1.0f / lacc[sub][r];

        #pragma unroll
        for (int r = 0; r < 4; ++r) {
            short* orow = O + ((size_t)(b * T_DIM) + i0 + sub * 64 + w * 16 + quad * 4 + r) * C_DIM + h * HS;
            #pragma unroll
            for (int dg = 0; dg < 4; ++dg)
                orow[dg * 16 + l16] = f2bf(oacc[sub][dg][r] * linv[r]);
        }
    }
}

// ---------------------------------------------------------------------------
// ws layout (bytes), NB = 2*M*C = 16.8MB, WB = 2*C*C = 2.1MB:
//   [0]      xb bf16 (reused as Ob after QKV gemm)
//   [NB]     QKVb bf16 [M,3C]  (3*NB; V cols unwritten — V goes direct to Vt)
//   [4NB]    Vt bf16 [B*NH,HS,T]
//   [5NB]    W3b (Wq|Wk|Wv rows, 3*WB) | Wob (WB)      total 92.4MB
// ---------------------------------------------------------------------------
extern "C" void kernel_launch(void* const* d_in, const int* in_sizes, int n_in,
                              void* d_out, int out_size, void* d_ws, size_t ws_size,
                              hipStream_t stream) {
    const float* x  = (const float*)d_in[0];
    const float* Wk = (const float*)d_in[1];
    const float* Wq = (const float*)d_in[2];
    const float* Wv = (const float*)d_in[3];
    const float* Wo = (const float*)d_in[4];
    float* out = (float*)d_out;

    const int M = B_DIM * T_DIM;                       // 8192
    const size_t NE = (size_t)M * C_DIM;               // 8.4M
    const size_t NB = 2 * NE;                          // bytes
    const size_t WB = (size_t)2 * C_DIM * C_DIM;

    char* ws = (char*)d_ws;
    short* xb   = (short*)(ws);
    short* Ob   = xb;                                  // reuse after QKV gemm
    short* QKVb = (short*)(ws + NB);
    short* Vtb  = (short*)(ws + 4 * NB);
    short* W3b  = (short*)(ws + 5 * NB);               // [3C, C] rows: Wq|Wk|Wv (then Wob)
    short* Wob  = (short*)(ws + 5 * NB + 3 * WB);

    // all casts in one launch (Wq pre-scaled by log2(e)/8)
    cast_all<<<dim3(XBLK + 4 * WBLK), 256, 0, stream>>>(
        x, Wq, Wk, Wv, Wo, xb, W3b);

    // fused QKV projection + V-transpose epilogue (wide-wave v2, grid 768 =
    // exactly 3 blocks/CU)
    gemm_bt_wide<2><<<dim3((QKV_LD / 256) * (M / 128)), 256, 0, stream>>>(
        xb, W3b, QKVb, Vtb, M, QKV_LD, C_DIM);

    // attention (2x q-merge, 1024 blocks = 4 blocks/CU, head-locality swizzle)
    attn_mfma3<<<dim3(T_DIM / (64 * QSUB) * B_DIM * NHEAD), 256, 0, stream>>>(
        QKVb, QKVb + C_DIM, Vtb, Ob);

    // output projection (8ph 512-thr, grid 256 = one full round, fp32 out)
    gemm_bt_8ph<0><<<dim3((C_DIM / 256) * (M / 128)), 512, 0, stream>>>(
        Ob, Wob, out, nullptr, M, C_DIM, C_DIM);
}